// Round 4
// baseline (917.325 us; speedup 1.0000x reference)
//
#include <hip/hip_runtime.h>
#include <hip/hip_bf16.h>

// VQ-VAE forward loss on MI355X.
// loss = 2.25 * mean((emb[argmin] - x)^2)
//      = 2.25/(N*D) * [ sum(x^2) + sum_n min_k(||e_k||^2 - 2 x_n.e_k) ]
//
// R6: (a) spill fix — WRITE_SIZE=164MB in R4/R5 was identical => epilogue fold
//     (rm[16] arrays + 64 AGPR acc) spilled ~20 regs/thread. Fold is now
//     streamed scalar-at-a-time (no arrays).
//     (b) B-latency fix — B staged into LDS in EXACT fragment order via
//     global_load_lds (per-lane global source, linear LDS dest => zero bank
//     conflicts, zero staging VGPRs), double-buffered per 32-col chunk and
//     issued a full chunk ahead (~500 cyc cover vs ~200 cyc L2 latency).
//     A tile (x) reg-staged 1 float4/thread/chunk, convert-late, dbuf.
//     LDS 76KB, regs ~50 VGPR + 64 AGPR => 2 blocks/CU anti-phased.

#define NROWS (64 * 4096)   // 262144
#define DDIM  480
#define KCODES 512
#define BM    64            // rows per block
#define BK2   32            // cols per chunk = 2 MFMA k-steps of 16
#define NCH2  15            // 480 / 32
#define ALDSP 40            // padded A row stride (bf16 elems) = 80 B
#define NT    512           // threads per block (8 waves)

typedef __bf16 bf16x8 __attribute__((ext_vector_type(8)));
typedef float  f32x16 __attribute__((ext_vector_type(16)));

typedef const unsigned int __attribute__((address_space(1)))* as1_u32p;
typedef unsigned int __attribute__((address_space(3)))* as3_u32p;

__device__ __forceinline__ void async_cp16(const void* g, void* l) {
    __builtin_amdgcn_global_load_lds((as1_u32p)g, (as3_u32p)l, 16, 0, 0);
}

__device__ __forceinline__ ushort f2bf(float v) {
    union { float f; unsigned u; } c; c.f = v;
    unsigned u = c.u;
    u += 0x7fffu + ((u >> 16) & 1u);   // round-to-nearest-even
    return (ushort)(u >> 16);
}

// Convert codebook to bf16 in ws, compute ||e_k||^2 (fp32 exact), zero d_out.
__global__ void vq_setup(const float* __restrict__ e, ushort* __restrict__ ebf,
                         float* __restrict__ esq, float* __restrict__ out) {
    const int k = blockIdx.x;
    const int t = threadIdx.x;
    if (k == 0 && t == 0) out[0] = 0.0f;
    float s = 0.0f;
    for (int d = t; d < DDIM; d += 64) {
        float v = e[k * DDIM + d];
        s += v * v;
        ebf[k * DDIM + d] = f2bf(v);
    }
    #pragma unroll
    for (int m = 32; m >= 1; m >>= 1) s += __shfl_xor(s, m, 64);
    if (t == 0) esq[k] = s;
}

__global__ __launch_bounds__(NT, 4) void vq_main(const float* __restrict__ x,
        const ushort* __restrict__ ebf, const float* __restrict__ esq,
        float* __restrict__ out) {
    // B in fragment order: [slot][wave][kk][coltile][64 lanes * 16B]
    __shared__ ushort Bl[2][8][2][2][512];   // 65536 B
    __shared__ ushort Al[2][BM * ALDSP];     // 10240 B
    __shared__ float red[8 * BM];            // 2048 B
    __shared__ float redw[8];

    const int t    = threadIdx.x;
    const int wave = t >> 6;
    const int lane = t & 63;
    const int l31  = lane & 31;   // 32x32 MFMA row/col lane index
    const int hw   = lane >> 5;   // k-half

    const float* xb = x + (size_t)blockIdx.x * (BM * DDIM);

    // ---- A staging map: 1 float4/thread/chunk; row = t/8, 4 cols ----
    const int arow = t >> 3, ac4 = (t & 7) << 2;
    const float* xA = xb + arow * DDIM + ac4;
    const int la = arow * ALDSP + ac4;

    float xsq = 0.0f;

#define CVT_WRITE(S, V) do {                                               \
        xsq += (V).x*(V).x + (V).y*(V).y + (V).z*(V).z + (V).w*(V).w;      \
        ushort4 b_;                                                        \
        b_.x = f2bf((V).x); b_.y = f2bf((V).y);                            \
        b_.z = f2bf((V).z); b_.w = f2bf((V).w);                            \
        *(ushort4*)(&Al[S][la]) = b_;                                      \
    } while (0)

    // ---- per-wave code slice: 64 codes = 2 coltiles of 32 ----
    const int code0 = wave * 64;
    // fragment source: lane (l31,hw) of coltile ct reads
    //   ebf[code0 + ct*32 + l31][chunk*32 + kk*16 + hw*8 .. +8]
    const ushort* bsrc = ebf + (size_t)(code0 + l31) * DDIM + hw * 8;

#define B_ISSUE(NS, CH) do {                                               \
        const ushort* bs_ = bsrc + (CH) * BK2;                             \
        async_cp16(bs_,                  &Bl[NS][wave][0][0][0]);          \
        async_cp16(bs_ + 16,             &Bl[NS][wave][1][0][0]);          \
        async_cp16(bs_ + 32 * DDIM,      &Bl[NS][wave][0][1][0]);          \
        async_cp16(bs_ + 32 * DDIM + 16, &Bl[NS][wave][1][1][0]);          \
    } while (0)

    f32x16 acc00, acc01, acc10, acc11;
    #pragma unroll
    for (int j = 0; j < 16; ++j) { acc00[j] = 0.f; acc01[j] = 0.f; acc10[j] = 0.f; acc11[j] = 0.f; }

#define KSTEP(KK, S) do {                                                         \
        bf16x8 A0 = *(const bf16x8*)(&Al[S][l31 * ALDSP + (KK) * 16 + hw * 8]);   \
        bf16x8 A1 = *(const bf16x8*)(&Al[S][(32 + l31) * ALDSP + (KK) * 16 + hw * 8]); \
        bf16x8 B0 = *(const bf16x8*)(&Bl[S][wave][KK][0][lane * 8]);              \
        bf16x8 B1 = *(const bf16x8*)(&Bl[S][wave][KK][1][lane * 8]);              \
        acc00 = __builtin_amdgcn_mfma_f32_32x32x16_bf16(A0, B0, acc00, 0, 0, 0);  \
        acc01 = __builtin_amdgcn_mfma_f32_32x32x16_bf16(A0, B1, acc01, 0, 0, 0);  \
        acc10 = __builtin_amdgcn_mfma_f32_32x32x16_bf16(A1, B0, acc10, 0, 0, 0);  \
        acc11 = __builtin_amdgcn_mfma_f32_32x32x16_bf16(A1, B1, acc11, 0, 0, 0);  \
    } while (0)

    // ---- prologue: stage chunk 0 (A reg-path, B gload_lds) ----
    {
        float4 av0 = *(const float4*)xA;
        B_ISSUE(0, 0);
        asm volatile("s_waitcnt vmcnt(4)" ::: "memory");   // av0 landed; B0 in flight
        CVT_WRITE(0, av0);
    }

    // ---- main pipeline: 15 chunks of 32 cols (2 k-steps each) ----
    for (int c = 0; c < NCH2; ++c) {
        const int s = c & 1, ns = s ^ 1;
        // drains B_c gloads (vmcnt0, issued a full chunk ago) + A ds_writes
        __syncthreads();
        float4 av;
        if (c < NCH2 - 1) {
            av = *(const float4*)(xA + (c + 1) * BK2);   // oldest in queue
            B_ISSUE(ns, c + 1);                          // 4 gloads after it
        }
        KSTEP(0, s);
        KSTEP(1, s);
        if (c < NCH2 - 1) CVT_WRITE(ns, av);             // waits av (vmcnt(4))
    }

    // ---- streamed fold: min_k (esq[k] - 2*dot), no live arrays ----
    // acc row = r*32 + (j&3) + 8*(j>>2) + 4*hw, col(code) = code0 + c*32 + l31
    const float es0 = esq[code0 + l31];
    const float es1 = esq[code0 + 32 + l31];
    #pragma unroll
    for (int j = 0; j < 16; ++j) {
        float v = fminf(es0 - 2.0f * acc00[j], es1 - 2.0f * acc01[j]);
        v = fminf(v, __shfl_xor(v, 1, 64));
        v = fminf(v, __shfl_xor(v, 2, 64));
        v = fminf(v, __shfl_xor(v, 4, 64));
        v = fminf(v, __shfl_xor(v, 8, 64));
        v = fminf(v, __shfl_xor(v, 16, 64));
        if (l31 == 0) red[wave * 64 + (j & 3) + 8 * (j >> 2) + 4 * hw] = v;
        float u = fminf(es0 - 2.0f * acc10[j], es1 - 2.0f * acc11[j]);
        u = fminf(u, __shfl_xor(u, 1, 64));
        u = fminf(u, __shfl_xor(u, 2, 64));
        u = fminf(u, __shfl_xor(u, 4, 64));
        u = fminf(u, __shfl_xor(u, 8, 64));
        u = fminf(u, __shfl_xor(u, 16, 64));
        if (l31 == 0) red[wave * 64 + 32 + (j & 3) + 8 * (j >> 2) + 4 * hw] = u;
    }
    __syncthreads();

    // ---- combine: min across 8 waves per row, + sum(x^2), block reduce ----
    float val = xsq;
    if (t < 64) {
        float m0 = fminf(red[t],       red[64 + t]);
        float m1 = fminf(red[128 + t], red[192 + t]);
        float m2 = fminf(red[256 + t], red[320 + t]);
        float m3 = fminf(red[384 + t], red[448 + t]);
        val += fminf(fminf(m0, m1), fminf(m2, m3));
    }
    #pragma unroll
    for (int m = 32; m >= 1; m >>= 1) val += __shfl_xor(val, m, 64);
    if (lane == 0) redw[wave] = val;
    __syncthreads();
    if (t == 0) {
        const float SCALE = 2.25f / ((float)NROWS * (float)DDIM);
        float s = 0.f;
        #pragma unroll
        for (int w = 0; w < 8; ++w) s += redw[w];
        atomicAdd(out, s * SCALE);
    }
}

extern "C" void kernel_launch(void* const* d_in, const int* in_sizes, int n_in,
                              void* d_out, int out_size, void* d_ws, size_t ws_size,
                              hipStream_t stream) {
    (void)in_sizes; (void)n_in; (void)out_size; (void)ws_size;
    const float* x = (const float*)d_in[0];   // [262144, 480] fp32
    const float* e = (const float*)d_in[1];   // [512, 480] fp32
    float* out = (float*)d_out;               // scalar fp32
    ushort* ebf = (ushort*)d_ws;                              // 512*480*2 = 491520 B
    float*  esq = (float*)((char*)d_ws + KCODES * DDIM * 2);  // 512*4 B

    vq_setup<<<KCODES, 64, 0, stream>>>(e, ebf, esq, out);
    vq_main<<<NROWS / BM, NT, 0, stream>>>(x, ebf, esq, out);
}